// Round 12
// baseline (131.175 us; speedup 1.0000x reference)
//
#include <hip/hip_runtime.h>

#define W_ 160
#define H_ 128
#define C_ 32
#define D_ 48
#define HW_ (H_*W_)      // 20480
#define TX 16
#define TY 16
#define HPX 18
#define HPY 18
#define NHP (HPX*HPY)    // 324
#define NHPP 336         // padded to 21 MFMA tiles of 16
#define NT 21            // MFMA tiles
#define DSTW 29          // DL stride in u32 words (27 live cols, odd => bank-spread)

typedef _Float16 h8 __attribute__((ext_vector_type(8)));
typedef __fp16 fp16x2 __attribute__((ext_vector_type(2)));
typedef float f4 __attribute__((ext_vector_type(4)));

__device__ __forceinline__ _Float16 u2h(unsigned int u) {
    union { unsigned short s; _Float16 h; } x; x.s = (unsigned short)u; return x.h;
}
__device__ __forceinline__ unsigned int pkh2(float a, float b) {
    union { fp16x2 h; unsigned int u; } x;
    x.h = __builtin_amdgcn_cvt_pkrtz(a, b);
    return x.u;
}

__device__ __forceinline__ void inv4x4(const float* a, float* inv) {
    inv[0]  =  a[5]*a[10]*a[15] - a[5]*a[11]*a[14] - a[9]*a[6]*a[15] + a[9]*a[7]*a[14] + a[13]*a[6]*a[11] - a[13]*a[7]*a[10];
    inv[4]  = -a[4]*a[10]*a[15] + a[4]*a[11]*a[14] + a[8]*a[6]*a[15] - a[8]*a[7]*a[14] - a[12]*a[6]*a[11] + a[12]*a[7]*a[10];
    inv[8]  =  a[4]*a[9]*a[15]  - a[4]*a[11]*a[13] - a[8]*a[5]*a[15] + a[8]*a[7]*a[13] + a[12]*a[5]*a[11] - a[12]*a[7]*a[9];
    inv[12] = -a[4]*a[9]*a[14]  + a[4]*a[10]*a[13] + a[8]*a[5]*a[14] - a[8]*a[6]*a[13] - a[12]*a[5]*a[10] + a[12]*a[6]*a[9];
    inv[1]  = -a[1]*a[10]*a[15] + a[1]*a[11]*a[14] + a[9]*a[2]*a[15] - a[9]*a[3]*a[14] - a[13]*a[2]*a[11] + a[13]*a[3]*a[10];
    inv[5]  =  a[0]*a[10]*a[15] - a[0]*a[11]*a[14] - a[8]*a[2]*a[15] + a[8]*a[3]*a[14] + a[12]*a[2]*a[11] - a[12]*a[3]*a[10];
    inv[9]  = -a[0]*a[9]*a[15]  + a[0]*a[11]*a[13] + a[8]*a[1]*a[15] - a[8]*a[3]*a[13] - a[12]*a[1]*a[11] + a[12]*a[3]*a[9];
    inv[13] =  a[0]*a[9]*a[14]  - a[0]*a[10]*a[13] - a[8]*a[1]*a[14] + a[8]*a[2]*a[13] + a[12]*a[1]*a[10] - a[12]*a[2]*a[9];
    inv[2]  =  a[1]*a[6]*a[15]  - a[1]*a[7]*a[14]  - a[5]*a[2]*a[15] + a[5]*a[3]*a[14] + a[13]*a[2]*a[7]  - a[13]*a[3]*a[6];
    inv[6]  = -a[0]*a[6]*a[15]  + a[0]*a[7]*a[14]  + a[4]*a[2]*a[15] - a[4]*a[3]*a[14] - a[12]*a[2]*a[7]  + a[12]*a[3]*a[6];
    inv[10] =  a[0]*a[5]*a[15]  - a[0]*a[7]*a[13]  - a[4]*a[1]*a[15] + a[4]*a[3]*a[13] + a[12]*a[1]*a[7]  - a[12]*a[3]*a[5];
    inv[14] = -a[0]*a[5]*a[14]  + a[0]*a[6]*a[13]  + a[4]*a[1]*a[14] - a[4]*a[2]*a[13] - a[12]*a[1]*a[6]  + a[12]*a[2]*a[5];
    inv[3]  = -a[1]*a[6]*a[11]  + a[1]*a[7]*a[10]  + a[5]*a[2]*a[11] - a[5]*a[3]*a[10] - a[9]*a[2]*a[7]   + a[9]*a[3]*a[6];
    inv[7]  =  a[0]*a[6]*a[11]  - a[0]*a[7]*a[10]  - a[4]*a[2]*a[11] + a[4]*a[3]*a[10] + a[8]*a[2]*a[7]   - a[8]*a[3]*a[6];
    inv[11] = -a[0]*a[5]*a[11]  + a[0]*a[7]*a[9]   + a[4]*a[1]*a[11] - a[4]*a[3]*a[9]  - a[8]*a[1]*a[7]   + a[8]*a[3]*a[5];
    inv[15] =  a[0]*a[5]*a[10]  - a[0]*a[6]*a[9]   - a[4]*a[1]*a[10] + a[4]*a[2]*a[9]  + a[8]*a[1]*a[6]   - a[8]*a[2]*a[5];
    float det = a[0]*inv[0] + a[1]*inv[4] + a[2]*inv[8] + a[3]*inv[12];
    float id = 1.0f / det;
    for (int i = 0; i < 16; ++i) inv[i] *= id;
}

__device__ __forceinline__ void fuseProj(const float* proj, int i, float* F) {
    const float* A = proj + i*32;   // pair[0]
    const float* R = A + 16;        // pair[1]
    for (int r = 0; r < 3; ++r)
        for (int k = 0; k < 4; ++k)
            F[r*4+k] = R[r*4]*A[k] + R[r*4+1]*A[4+k] + R[r*4+2]*A[8+k];
    for (int k = 0; k < 4; ++k) F[12+k] = A[12+k];
}

// Fused setup: bx<320 -> feature transpose (float4 loads); bx==320 -> M only.
__global__ __launch_bounds__(256) void kS(const float* __restrict__ f,
                                          const float* __restrict__ proj,
                                          _Float16* __restrict__ ft,
                                          float* __restrict__ M) {
    __shared__ float t[64][33];
    const int bx = blockIdx.x, v = blockIdx.y;
    const int tid = threadIdx.x;
    if (bx < 320) {
        const int p0 = bx * 64;
        const int q = tid & 15;        // px-quad
        const int ch0 = tid >> 4;      // 16 channels per j-iter
        #pragma unroll
        for (int j = 0; j < 2; ++j) {
            const int ch = ch0 + j*16;
            const float4 v4 = *(const float4*)&f[(size_t)(v*C_ + ch)*HW_ + p0 + q*4];
            t[q*4 + 0][ch] = v4.x;
            t[q*4 + 1][ch] = v4.y;
            t[q*4 + 2][ch] = v4.z;
            t[q*4 + 3][ch] = v4.w;
        }
        __syncthreads();
        const int px = tid >> 2;
        const int c0 = (tid & 3) * 8;
        h8 o;
        #pragma unroll
        for (int k = 0; k < 8; ++k) o[k] = (_Float16)t[px][c0 + k];
        *(h8*)&ft[((size_t)(v*HW_ + p0 + px) << 5) + c0] = o;
    } else {
        if (v >= 4 || tid != 0) return;
        float F0[16], Fv[16], inv[16], P[12];
        fuseProj(proj, 0, F0);
        fuseProj(proj, v + 1, Fv);
        inv4x4(F0, inv);
        #pragma unroll
        for (int r = 0; r < 3; ++r)
            #pragma unroll
            for (int c = 0; c < 4; ++c) {
                float acc = 0.f;
                #pragma unroll
                for (int k = 0; k < 4; ++k) acc += Fv[r*4+k]*inv[k*4+c];
                P[r*4+c] = acc;
            }
        float* om = M + v*12;
        om[0]=P[0]; om[1]=P[1]; om[2]=P[2];
        om[3]=P[4]; om[4]=P[5]; om[5]=P[6];
        om[6]=P[8]; om[7]=P[9]; om[8]=P[10];
        om[9]=P[3]; om[10]=P[7]; om[11]=P[11];
    }
}

// Fused main, 2 depths/block, 256 threads — r11 verified base (55.7us) with
// the LAST un-pipelined memory dependency moved cross-pass:
//  view-0 of pass p+1 (5 shuffles + 4 corner loads) is issued during pass p,
//  right after p+1's projection — it flies under pass p's FMA tail, MFMA and
//  DL writes. Pass p+1's gather starts with view-0 register-resident; the
//  in-pass shuffle loop covers views 1-3 only. Same FP order (FMAs still
//  pok-guarded, v0->v3); loads with pokN=false read index 0 (safe).
// POST-MORTEM CHECK: VGPR must stay <=128 (keeps 4 waves/SIMD with the
// LDS-pinned 4 blocks/CU). Expect ~95-115.
__global__ __launch_bounds__(256) void kA(const _Float16* __restrict__ featH,
                                          const float* __restrict__ M,
                                          const float* __restrict__ dvals,
                                          const float* __restrict__ regw,
                                          float* __restrict__ Q) {
    __shared__ __align__(16) unsigned DLP[NHPP*DSTW];   // 38976 B

    const int tid = threadIdx.x;
    const int bx = blockIdx.x, by = blockIdx.y;
    const int d0 = blockIdx.z*2, d1 = d0 + 1;
    const int lane = tid & 63;
    const int wv = tid >> 6;       // 0..3
    const int n = lane & 15;       // px-in-tile (both roles)
    const int grp = lane >> 4;     // view (proj role) / channel group (gather role)
    const float dv0 = dvals[d0], dv1 = dvals[d1];
    // per-view projection constants (proj role: view = grp)
    const float* Mg = M + grp*12;
    const float P0 = Mg[0], P1 = Mg[1], P2 = Mg[2];
    const float P3 = Mg[3], P4 = Mg[4], P5 = Mg[5];
    const float P6 = Mg[6], P7 = Mg[7], P8 = Mg[8];
    const float tx = Mg[9], ty = Mg[10], tz = Mg[11];

    // B fragments: col = kd*9 + sp (kd-major), 27 live cols
    h8 bf0, bf1;
    {
        const int kb = grp * 8;
        #pragma unroll
        for (int j = 0; j < 8; ++j) {
            const int ch = kb + j;
            bf0[j] = (_Float16)regw[ch*27 + n];
            bf1[j] = (_Float16)((n < 11) ? regw[ch*27 + 16 + n] : 0.f);
        }
    }

    const h8 hz = {(_Float16)0,(_Float16)0,(_Float16)0,(_Float16)0,
                   (_Float16)0,(_Float16)0,(_Float16)0,(_Float16)0};
    const h8* F = (const h8*)featH;
    const f4 fz = {0.f, 0.f, 0.f, 0.f};

    // geometry for a given tile
    auto mk = [&](int tile, bool& pokO, int& rpO, int& lxO, int& lyO) {
        const int px = tile*16 + n;
        const int hx = px % HPX;
        const int hy = px / HPX;
        lxO = bx*TX + hx - 1;
        lyO = by*TY + hy - 1;
        pokO = (px < NHP) && (lxO >= 0) && (lxO < W_) && (lyO >= 0) && (lyO < H_);
        rpO = pokO ? (lyO*W_ + lxO) : 0;
    };

    // full projection for (lx,ly), both depths — identical math to r11
    auto PROJ = [&](bool pokI, int lxI, int lyI,
                    unsigned& pidxO, unsigned& pwaxO, unsigned& pwayO,
                    unsigned& pwbxO, unsigned& pwbyO) {
        const float xf = (float)lxI, yf = (float)lyI;
        const float rx = fmaf(P0, xf, fmaf(P1, yf, P2));
        const float ry = fmaf(P3, xf, fmaf(P4, yf, P5));
        const float rz = fmaf(P6, xf, fmaf(P7, yf, P8));
        const float z0 = rz*dv0 + tz;
        const float rz0 = 1.0f / z0;
        const float pxf0 = fminf(fmaxf((rx*dv0 + tx)*rz0, -8.f), 168.f);
        const float pyf0 = fminf(fmaxf((ry*dv0 + ty)*rz0, -8.f), 136.f);
        const float fx = floorf(pxf0), fy = floorf(pyf0);
        const float mxl = (fx >= 0.f  && fx <= 159.f) ? 1.f : 0.f;
        const float mxh = (fx >= -1.f && fx <= 158.f) ? 1.f : 0.f;
        const float myl = (fy >= 0.f  && fy <= 127.f) ? 1.f : 0.f;
        const float myh = (fy >= -1.f && fy <= 126.f) ? 1.f : 0.f;
        const int xs = (int)fminf(fmaxf(fx + 1.f, 0.f), 160.f);
        const int ys = (int)fminf(fmaxf(fy + 1.f, 0.f), 128.f);
        const int x0 = max(xs-1, 0), x1 = min(xs, W_-1);
        const int y0 = max(ys-1, 0), y1 = min(ys, H_-1);
        pidxO = (unsigned)x0 | ((unsigned)x1 << 8)
              | ((unsigned)y0 << 16) | ((unsigned)y1 << 24);
        const float wx1a = pxf0 - fx, wy1a = pyf0 - fy;
        pwaxO = pkh2((1.f - wx1a)*mxl, wx1a*mxh);
        pwayO = pkh2((1.f - wy1a)*myl, wy1a*myh);
        const float z1 = rz*dv1 + tz;
        const float rz1 = 1.0f / z1;
        const float pxf1 = fminf(fmaxf((rx*dv1 + tx)*rz1, -8.f), 168.f);
        const float pyf1 = fminf(fmaxf((ry*dv1 + ty)*rz1, -8.f), 136.f);
        const float wx1b = pxf1 - fx, wy1b = pyf1 - fy;
        pwbxO = pkh2((1.f - wx1b)*mxl, wx1b*mxh);
        pwbyO = pkh2((1.f - wy1b)*myl, wy1b*myh);
        if (!pokI) { pwaxO = 0u; pwayO = 0u; pwbxO = 0u; pwbyO = 0u; }
    };

    // view-0 corner loads from a packed index (index 0 when invalid — safe)
    auto LD0 = [&](unsigned i0, h8& c00, h8& c10, h8& c01, h8& c11) {
        const int x0 = i0 & 0xff, x1 = (i0 >> 8) & 0xff;
        const int y0W = ((i0 >> 16) & 0xff) * W_;
        const int y1W = (i0 >> 24) * W_;
        const h8* Fv = F + (size_t)1*HW_*4;
        c00 = Fv[(size_t)(y0W+x0)*4 + grp];
        c10 = Fv[(size_t)(y0W+x1)*4 + grp];
        c01 = Fv[(size_t)(y1W+x0)*4 + grp];
        c11 = Fv[(size_t)(y1W+x1)*4 + grp];
    };

    // prologue: pass-0 geometry + ref-feature + projection + view-0 prefetch
    bool pok; int rp, lx, ly;
    mk(wv, pok, rp, lx, ly);
    h8 fr = F[(size_t)rp*4 + grp];
    unsigned pidx, pwax, pway, pwbx, pwby;
    PROJ(pok, lx, ly, pidx, pwax, pway, pwbx, pwby);
    unsigned i0c  = (unsigned)__shfl((int)pidx, n, 64);
    unsigned ax0c = (unsigned)__shfl((int)pwax, n, 64);
    unsigned ay0c = (unsigned)__shfl((int)pway, n, 64);
    unsigned bx0c = (unsigned)__shfl((int)pwbx, n, 64);
    unsigned by0c = (unsigned)__shfl((int)pwby, n, 64);
    h8 c00c, c10c, c01c, c11c;
    LD0(i0c, c00c, c10c, c01c, c11c);

    #pragma unroll 1
    for (int pass = 0; pass < 6; ++pass) {
        const int tile = pass*4 + wv;          // wave-uniform

        // ---- next pass: geometry + fr + projection + VIEW-0 prefetch ----
        bool pokN = false; int lxN = 0, lyN = 0;
        h8 frN = hz;
        unsigned pidxN = 0u, pwaxN = 0u, pwayN = 0u, pwbxN = 0u, pwbyN = 0u;
        unsigned i0N = 0u, ax0N = 0u, ay0N = 0u, bx0N = 0u, by0N = 0u;
        h8 c00N = hz, c10N = hz, c01N = hz, c11N = hz;
        if (pass < 5) {
            int rpN;
            mk(tile + 4, pokN, rpN, lxN, lyN);
            frN = F[(size_t)rpN*4 + grp];
            PROJ(pokN, lxN, lyN, pidxN, pwaxN, pwayN, pwbxN, pwbyN);
            i0N  = (unsigned)__shfl((int)pidxN, n, 64);
            ax0N = (unsigned)__shfl((int)pwaxN, n, 64);
            ay0N = (unsigned)__shfl((int)pwayN, n, 64);
            bx0N = (unsigned)__shfl((int)pwbxN, n, 64);
            by0N = (unsigned)__shfl((int)pwbyN, n, 64);
            LD0(i0N, c00N, c10N, c01N, c11N);
        }

        if (tile < NT) {
            // ---- shuffles for views 1..3 (view 0 already prefetched) ----
            unsigned iv[4], axv[4], ayv[4], bxv[4], byv[4];
            iv[0] = i0c; axv[0] = ax0c; ayv[0] = ay0c; bxv[0] = bx0c; byv[0] = by0c;
            #pragma unroll
            for (int v = 1; v < 4; ++v) {
                const int src = v*16 + n;
                iv[v]  = (unsigned)__shfl((int)pidx, src, 64);
                axv[v] = (unsigned)__shfl((int)pwax, src, 64);
                ayv[v] = (unsigned)__shfl((int)pway, src, 64);
                bxv[v] = (unsigned)__shfl((int)pwbx, src, 64);
                byv[v] = (unsigned)__shfl((int)pwby, src, 64);
            }

            // ---- gather: view-0 corners already resident, rotate 1..3 ----
            h8 var0 = hz, var1 = hz;
            h8 s0 = hz, q0 = hz, s1 = hz, q1 = hz;
            if (pok) {
                s0 = fr; q0 = fr*fr; s1 = fr; q1 = q0;
            }

            h8 f00 = c00c, f10 = c10c, f01 = c01c, f11 = c11c;

            #pragma unroll
            for (int v = 0; v < 4; ++v) {
                // issue view v+1's corner loads (params already shuffled)
                h8 n00 = hz, n10 = hz, n01 = hz, n11 = hz;
                if (v < 3) {
                    if (pok) {
                        const unsigned ii = iv[v+1];
                        const int x0 = ii & 0xff, x1 = (ii >> 8) & 0xff;
                        const int y0W = ((ii >> 16) & 0xff) * W_;
                        const int y1W = (ii >> 24) * W_;
                        const h8* Fv = F + (size_t)(v+2)*HW_*4;
                        n00 = Fv[(size_t)(y0W+x0)*4 + grp];
                        n10 = Fv[(size_t)(y0W+x1)*4 + grp];
                        n01 = Fv[(size_t)(y1W+x0)*4 + grp];
                        n11 = Fv[(size_t)(y1W+x1)*4 + grp];
                    }
                }
                if (pok) {
                    const _Float16 wx0a = u2h(axv[v]), wx1a = u2h(axv[v] >> 16);
                    const _Float16 wy0a = u2h(ayv[v]), wy1a = u2h(ayv[v] >> 16);
                    const h8 t0a = f00*wx0a + f10*wx1a;
                    const h8 t1a = f01*wx0a + f11*wx1a;
                    const h8 g0 = t0a*wy0a + t1a*wy1a;
                    s0 += g0; q0 += g0*g0;
                    const _Float16 wx0b = u2h(bxv[v]), wx1b = u2h(bxv[v] >> 16);
                    const _Float16 wy0b = u2h(byv[v]), wy1b = u2h(byv[v] >> 16);
                    const h8 t0b = f00*wx0b + f10*wx1b;
                    const h8 t1b = f01*wx0b + f11*wx1b;
                    const h8 g1 = t0b*wy0b + t1b*wy1b;
                    s1 += g1; q1 += g1*g1;
                }
                // rotate (renamed by full unroll, no movs)
                f00 = n00; f10 = n10; f01 = n01; f11 = n11;
            }

            if (pok) {
                const _Float16 c5 = (_Float16)0.2f;
                const h8 sa = s0 * c5, sb = s1 * c5;
                var0 = q0*c5 - sa*sa;
                var1 = q1*c5 - sb*sb;
            }
            // variance already in MFMA A-layout: lane holds A[px=n][k=grp*8..+8]
            const f4 a0 = __builtin_amdgcn_mfma_f32_16x16x32_f16(var0, bf0, fz, 0, 0, 0);
            const f4 b0 = __builtin_amdgcn_mfma_f32_16x16x32_f16(var0, bf1, fz, 0, 0, 0);
            const f4 a1 = __builtin_amdgcn_mfma_f32_16x16x32_f16(var1, bf0, fz, 0, 0, 0);
            const f4 b1 = __builtin_amdgcn_mfma_f32_16x16x32_f16(var1, bf1, fz, 0, 0, 0);
            const int rbase = tile*16 + grp*4;
            #pragma unroll
            for (int r = 0; r < 4; ++r) {
                unsigned* dr = &DLP[(rbase + r)*DSTW];
                dr[n] = pkh2(a0[r], a1[r]);
                if (n < 11) dr[16 + n] = pkh2(b0[r], b1[r]);
            }
        }

        // rotate pass state
        pok = pokN; lx = lxN; ly = lyN; fr = frN;
        pidx = pidxN; pwax = pwaxN; pway = pwayN; pwbx = pwbxN; pwby = pwbyN;
        i0c = i0N; ax0c = ax0N; ay0c = ay0N; bx0c = bx0N; by0c = by0N;
        c00c = c00N; c10c = c10N; c01c = c01N; c11c = c11N;
    }
    __syncthreads();

    // ---- 27-term spatial shifted sum -> Q[kd][d][p], both depths ----
    {
        const int x = tid & 15;
        const int y = tid >> 4;
        float c00 = 0.f, c01 = 0.f, c02 = 0.f;
        float c10 = 0.f, c11 = 0.f, c12 = 0.f;
        #pragma unroll
        for (int jy = 0; jy < 3; ++jy) {
            #pragma unroll
            for (int jx = 0; jx < 3; ++jx) {
                const int sp = jy*3 + jx;
                const unsigned* dr = &DLP[((y + jy)*HPX + (x + jx))*DSTW];
                const unsigned u0 = dr[sp];
                const unsigned u1 = dr[9 + sp];
                const unsigned u2 = dr[18 + sp];
                c00 += (float)u2h(u0);  c10 += (float)u2h(u0 >> 16);
                c01 += (float)u2h(u1);  c11 += (float)u2h(u1 >> 16);
                c02 += (float)u2h(u2);  c12 += (float)u2h(u2 >> 16);
            }
        }
        const int p = (by*TY + y)*W_ + bx*TX + x;
        Q[(size_t)(0*D_ + d0)*HW_ + p] = c00;
        Q[(size_t)(1*D_ + d0)*HW_ + p] = c01;
        Q[(size_t)(2*D_ + d0)*HW_ + p] = c02;
        Q[(size_t)(0*D_ + d1)*HW_ + p] = c10;
        Q[(size_t)(1*D_ + d1)*HW_ + p] = c11;
        Q[(size_t)(2*D_ + d1)*HW_ + p] = c12;
    }
}

// Finalize: combine depth taps, softmax over D, depth + confidence.
// ROUND-6 VERIFIED VERSION: 256-thread blocks, wave w handles 12 depths for
// 64 px; block combine via 5 KB LDS.
__global__ __launch_bounds__(256) void kB(const float* __restrict__ Q,
                                          const float* __restrict__ dvals,
                                          float* __restrict__ out) {
    __shared__ float Rm[4][64], Sm[4][64], Sd[4][64], Si[4][64], Cf[4][64];
    const int tid = threadIdx.x;
    const int l = tid & 63;
    const int w = tid >> 6;
    const int p = blockIdx.x*64 + l;
    const int db = w*12;
    const float* Q0 = Q;
    const float* Q1 = Q + (size_t)D_*HW_;
    const float* Q2 = Q + (size_t)2*D_*HW_;

    float c[12];
    #pragma unroll
    for (int j = 0; j < 12; ++j) {
        const int dd = db + j;
        float v = Q1[dd*HW_ + p];
        if (dd > 0)     v += Q0[(dd-1)*HW_ + p];
        if (dd < D_-1)  v += Q2[(dd+1)*HW_ + p];
        c[j] = v;
    }
    float lm = c[0];
    #pragma unroll
    for (int j = 1; j < 12; ++j) lm = fmaxf(lm, c[j]);
    Rm[w][l] = lm;
    __syncthreads();
    const float gm = fmaxf(fmaxf(Rm[0][l], Rm[1][l]), fmaxf(Rm[2][l], Rm[3][l]));

    float e[12];
    float ls = 0.f, lsd = 0.f, lsi = 0.f;
    #pragma unroll
    for (int j = 0; j < 12; ++j) {
        const int dd = db + j;
        const float ev = __expf(c[j] - gm);
        e[j] = ev;
        ls  += ev;
        lsd += ev * dvals[dd];
        lsi += ev * (float)dd;
    }
    Sm[w][l] = ls; Sd[w][l] = lsd; Si[w][l] = lsi;
    __syncthreads();
    const float ts  = Sm[0][l] + Sm[1][l] + Sm[2][l] + Sm[3][l];
    const float tsd = Sd[0][l] + Sd[1][l] + Sd[2][l] + Sd[3][l];
    const float tsi = Si[0][l] + Si[1][l] + Si[2][l] + Si[3][l];
    const float is = 1.f / ts;
    int di = (int)(tsi * is);
    di = di < 0 ? 0 : (di > D_-1 ? D_-1 : di);

    float lc = 0.f;
    #pragma unroll
    for (int j = 0; j < 12; ++j) {
        const int dd = db + j;
        lc += ((dd >= di-1) && (dd <= di+2)) ? e[j] : 0.f;
    }
    Cf[w][l] = lc;
    __syncthreads();
    if (w == 0) {
        out[p] = tsd * is;
        out[HW_ + p] = (Cf[0][l] + Cf[1][l] + Cf[2][l] + Cf[3][l]) * is;
    }
}

extern "C" void kernel_launch(void* const* d_in, const int* in_sizes, int n_in,
                              void* d_out, int out_size, void* d_ws, size_t ws_size,
                              hipStream_t stream) {
    const float* features = (const float*)d_in[0];
    const float* proj     = (const float*)d_in[1];
    const float* dvals    = (const float*)d_in[2];
    const float* regw     = (const float*)d_in[3];
    float* out = (float*)d_out;

    _Float16* featH = (_Float16*)d_ws;                       // 5*HW*32 f16 = 6.55 MB
    float* M  = (float*)(featH + (size_t)5*HW_*C_);          // 48 floats (+pad)
    float* Q  = M + 64;                                      // 3*48*HW f32 = 11.8 MB

    kS<<<dim3(321, 5), 256, 0, stream>>>(features, proj, featH, M);
    kA<<<dim3(W_/TX, H_/TY, D_/2), 256, 0, stream>>>(featH, M, dvals, regw, Q);
    kB<<<HW_/64, 256, 0, stream>>>(Q, dvals, out);
}

// Round 13
// 127.349 us; speedup vs baseline: 1.0300x; 1.0300x over previous
//
#include <hip/hip_runtime.h>

#define W_ 160
#define H_ 128
#define C_ 32
#define D_ 48
#define HW_ (H_*W_)      // 20480
#define TX 16
#define TY 16
#define HPX 18
#define HPY 18
#define NHP (HPX*HPY)    // 324
#define NHPP 336         // padded to 21 MFMA tiles of 16
#define NT 21            // MFMA tiles
#define DSTW 29          // DL stride in u32 words (27 live cols, odd => bank-spread)

typedef _Float16 h8 __attribute__((ext_vector_type(8)));
typedef __fp16 fp16x2 __attribute__((ext_vector_type(2)));
typedef float f4 __attribute__((ext_vector_type(4)));

__device__ __forceinline__ _Float16 u2h(unsigned int u) {
    union { unsigned short s; _Float16 h; } x; x.s = (unsigned short)u; return x.h;
}
__device__ __forceinline__ unsigned int pkh2(float a, float b) {
    union { fp16x2 h; unsigned int u; } x;
    x.h = __builtin_amdgcn_cvt_pkrtz(a, b);
    return x.u;
}

__device__ __forceinline__ void inv4x4(const float* a, float* inv) {
    inv[0]  =  a[5]*a[10]*a[15] - a[5]*a[11]*a[14] - a[9]*a[6]*a[15] + a[9]*a[7]*a[14] + a[13]*a[6]*a[11] - a[13]*a[7]*a[10];
    inv[4]  = -a[4]*a[10]*a[15] + a[4]*a[11]*a[14] + a[8]*a[6]*a[15] - a[8]*a[7]*a[14] - a[12]*a[6]*a[11] + a[12]*a[7]*a[10];
    inv[8]  =  a[4]*a[9]*a[15]  - a[4]*a[11]*a[13] - a[8]*a[5]*a[15] + a[8]*a[7]*a[13] + a[12]*a[5]*a[11] - a[12]*a[7]*a[9];
    inv[12] = -a[4]*a[9]*a[14]  + a[4]*a[10]*a[13] + a[8]*a[5]*a[14] - a[8]*a[6]*a[13] - a[12]*a[5]*a[10] + a[12]*a[6]*a[9];
    inv[1]  = -a[1]*a[10]*a[15] + a[1]*a[11]*a[14] + a[9]*a[2]*a[15] - a[9]*a[3]*a[14] - a[13]*a[2]*a[11] + a[13]*a[3]*a[10];
    inv[5]  =  a[0]*a[10]*a[15] - a[0]*a[11]*a[14] - a[8]*a[2]*a[15] + a[8]*a[3]*a[14] + a[12]*a[2]*a[11] - a[12]*a[3]*a[10];
    inv[9]  = -a[0]*a[9]*a[15]  + a[0]*a[11]*a[13] + a[8]*a[1]*a[15] - a[8]*a[3]*a[13] - a[12]*a[1]*a[11] + a[12]*a[3]*a[9];
    inv[13] =  a[0]*a[9]*a[14]  - a[0]*a[10]*a[13] - a[8]*a[1]*a[14] + a[8]*a[2]*a[13] + a[12]*a[1]*a[10] - a[12]*a[2]*a[9];
    inv[2]  =  a[1]*a[6]*a[15]  - a[1]*a[7]*a[14]  - a[5]*a[2]*a[15] + a[5]*a[3]*a[14] + a[13]*a[2]*a[7]  - a[13]*a[3]*a[6];
    inv[6]  = -a[0]*a[6]*a[15]  + a[0]*a[7]*a[14]  + a[4]*a[2]*a[15] - a[4]*a[3]*a[14] - a[12]*a[2]*a[7]  + a[12]*a[3]*a[6];
    inv[10] =  a[0]*a[5]*a[15]  - a[0]*a[7]*a[13]  - a[4]*a[1]*a[15] + a[4]*a[3]*a[13] + a[12]*a[1]*a[7]  - a[12]*a[3]*a[5];
    inv[14] = -a[0]*a[5]*a[14]  + a[0]*a[6]*a[13]  + a[4]*a[1]*a[14] - a[4]*a[2]*a[13] - a[12]*a[1]*a[6]  + a[12]*a[2]*a[5];
    inv[3]  = -a[1]*a[6]*a[11]  + a[1]*a[7]*a[10]  + a[5]*a[2]*a[11] - a[5]*a[3]*a[10] - a[9]*a[2]*a[7]   + a[9]*a[3]*a[6];
    inv[7]  =  a[0]*a[6]*a[11]  - a[0]*a[7]*a[10]  - a[4]*a[2]*a[11] + a[4]*a[3]*a[10] + a[8]*a[2]*a[7]   - a[8]*a[3]*a[6];
    inv[11] = -a[0]*a[5]*a[11]  + a[0]*a[7]*a[9]   + a[4]*a[1]*a[11] - a[4]*a[3]*a[9]  - a[8]*a[1]*a[7]   + a[8]*a[3]*a[5];
    inv[15] =  a[0]*a[5]*a[10]  - a[0]*a[6]*a[9]   - a[4]*a[1]*a[10] + a[4]*a[2]*a[9]  + a[8]*a[1]*a[6]   - a[8]*a[2]*a[5];
    float det = a[0]*inv[0] + a[1]*inv[4] + a[2]*inv[8] + a[3]*inv[12];
    float id = 1.0f / det;
    for (int i = 0; i < 16; ++i) inv[i] *= id;
}

__device__ __forceinline__ void fuseProj(const float* proj, int i, float* F) {
    const float* A = proj + i*32;   // pair[0]
    const float* R = A + 16;        // pair[1]
    for (int r = 0; r < 3; ++r)
        for (int k = 0; k < 4; ++k)
            F[r*4+k] = R[r*4]*A[k] + R[r*4+1]*A[4+k] + R[r*4+2]*A[8+k];
    for (int k = 0; k < 4; ++k) F[12+k] = A[12+k];
}

// Fused setup: bx<320 -> feature transpose (float4 loads); bx==320 -> M only.
__global__ __launch_bounds__(256) void kS(const float* __restrict__ f,
                                          const float* __restrict__ proj,
                                          _Float16* __restrict__ ft,
                                          float* __restrict__ M) {
    __shared__ float t[64][33];
    const int bx = blockIdx.x, v = blockIdx.y;
    const int tid = threadIdx.x;
    if (bx < 320) {
        const int p0 = bx * 64;
        const int q = tid & 15;        // px-quad
        const int ch0 = tid >> 4;      // 16 channels per j-iter
        #pragma unroll
        for (int j = 0; j < 2; ++j) {
            const int ch = ch0 + j*16;
            const float4 v4 = *(const float4*)&f[(size_t)(v*C_ + ch)*HW_ + p0 + q*4];
            t[q*4 + 0][ch] = v4.x;
            t[q*4 + 1][ch] = v4.y;
            t[q*4 + 2][ch] = v4.z;
            t[q*4 + 3][ch] = v4.w;
        }
        __syncthreads();
        const int px = tid >> 2;
        const int c0 = (tid & 3) * 8;
        h8 o;
        #pragma unroll
        for (int k = 0; k < 8; ++k) o[k] = (_Float16)t[px][c0 + k];
        *(h8*)&ft[((size_t)(v*HW_ + p0 + px) << 5) + c0] = o;
    } else {
        if (v >= 4 || tid != 0) return;
        float F0[16], Fv[16], inv[16], P[12];
        fuseProj(proj, 0, F0);
        fuseProj(proj, v + 1, Fv);
        inv4x4(F0, inv);
        #pragma unroll
        for (int r = 0; r < 3; ++r)
            #pragma unroll
            for (int c = 0; c < 4; ++c) {
                float acc = 0.f;
                #pragma unroll
                for (int k = 0; k < 4; ++k) acc += Fv[r*4+k]*inv[k*4+c];
                P[r*4+c] = acc;
            }
        float* om = M + v*12;
        om[0]=P[0]; om[1]=P[1]; om[2]=P[2];
        om[3]=P[4]; om[4]=P[5]; om[5]=P[6];
        om[6]=P[8]; om[7]=P[9]; om[8]=P[10];
        om[9]=P[3]; om[10]=P[7]; om[11]=P[11];
    }
}

// Fused main, 2 depths/block, 256 threads — EXACT r11 VERIFIED VERSION
// (55.7us kA, VGPR 64): 1-deep rotating view pipeline + batched shuffles +
// cross-pass PROJ + fr prefetch + RX-inline. Deeper pipelines regress:
// r8 2-deep corners = 61us/VGPR 72; r12 view-0 cross-pass staging =
// 59us/VGPR 76, occupancy 30->24.5%. Register pressure beyond ~64 costs
// more than the hidden latency is worth at 16 waves/CU.
__global__ __launch_bounds__(256) void kA(const _Float16* __restrict__ featH,
                                          const float* __restrict__ M,
                                          const float* __restrict__ dvals,
                                          const float* __restrict__ regw,
                                          float* __restrict__ Q) {
    __shared__ __align__(16) unsigned DLP[NHPP*DSTW];   // 38976 B

    const int tid = threadIdx.x;
    const int bx = blockIdx.x, by = blockIdx.y;
    const int d0 = blockIdx.z*2, d1 = d0 + 1;
    const int lane = tid & 63;
    const int wv = tid >> 6;       // 0..3
    const int n = lane & 15;       // px-in-tile (both roles)
    const int grp = lane >> 4;     // view (proj role) / channel group (gather role)
    const float dv0 = dvals[d0], dv1 = dvals[d1];
    // per-view projection constants (proj role: view = grp)
    const float* Mg = M + grp*12;
    const float P0 = Mg[0], P1 = Mg[1], P2 = Mg[2];
    const float P3 = Mg[3], P4 = Mg[4], P5 = Mg[5];
    const float P6 = Mg[6], P7 = Mg[7], P8 = Mg[8];
    const float tx = Mg[9], ty = Mg[10], tz = Mg[11];

    // B fragments: col = kd*9 + sp (kd-major), 27 live cols
    h8 bf0, bf1;
    {
        const int kb = grp * 8;
        #pragma unroll
        for (int j = 0; j < 8; ++j) {
            const int ch = kb + j;
            bf0[j] = (_Float16)regw[ch*27 + n];
            bf1[j] = (_Float16)((n < 11) ? regw[ch*27 + 16 + n] : 0.f);
        }
    }

    const h8 hz = {(_Float16)0,(_Float16)0,(_Float16)0,(_Float16)0,
                   (_Float16)0,(_Float16)0,(_Float16)0,(_Float16)0};
    const h8* F = (const h8*)featH;
    const f4 fz = {0.f, 0.f, 0.f, 0.f};

    // geometry for a given tile
    auto mk = [&](int tile, bool& pokO, int& rpO, int& lxO, int& lyO) {
        const int px = tile*16 + n;
        const int hx = px % HPX;
        const int hy = px / HPX;
        lxO = bx*TX + hx - 1;
        lyO = by*TY + hy - 1;
        pokO = (px < NHP) && (lxO >= 0) && (lxO < W_) && (lyO >= 0) && (lyO < H_);
        rpO = pokO ? (lyO*W_ + lxO) : 0;
    };

    // full projection for (lx,ly), both depths
    auto PROJ = [&](bool pokI, int lxI, int lyI,
                    unsigned& pidxO, unsigned& pwaxO, unsigned& pwayO,
                    unsigned& pwbxO, unsigned& pwbyO) {
        const float xf = (float)lxI, yf = (float)lyI;
        const float rx = fmaf(P0, xf, fmaf(P1, yf, P2));
        const float ry = fmaf(P3, xf, fmaf(P4, yf, P5));
        const float rz = fmaf(P6, xf, fmaf(P7, yf, P8));
        const float z0 = rz*dv0 + tz;
        const float rz0 = 1.0f / z0;
        const float pxf0 = fminf(fmaxf((rx*dv0 + tx)*rz0, -8.f), 168.f);
        const float pyf0 = fminf(fmaxf((ry*dv0 + ty)*rz0, -8.f), 136.f);
        const float fx = floorf(pxf0), fy = floorf(pyf0);
        const float mxl = (fx >= 0.f  && fx <= 159.f) ? 1.f : 0.f;
        const float mxh = (fx >= -1.f && fx <= 158.f) ? 1.f : 0.f;
        const float myl = (fy >= 0.f  && fy <= 127.f) ? 1.f : 0.f;
        const float myh = (fy >= -1.f && fy <= 126.f) ? 1.f : 0.f;
        const int xs = (int)fminf(fmaxf(fx + 1.f, 0.f), 160.f);
        const int ys = (int)fminf(fmaxf(fy + 1.f, 0.f), 128.f);
        const int x0 = max(xs-1, 0), x1 = min(xs, W_-1);
        const int y0 = max(ys-1, 0), y1 = min(ys, H_-1);
        pidxO = (unsigned)x0 | ((unsigned)x1 << 8)
              | ((unsigned)y0 << 16) | ((unsigned)y1 << 24);
        const float wx1a = pxf0 - fx, wy1a = pyf0 - fy;
        pwaxO = pkh2((1.f - wx1a)*mxl, wx1a*mxh);
        pwayO = pkh2((1.f - wy1a)*myl, wy1a*myh);
        const float z1 = rz*dv1 + tz;
        const float rz1 = 1.0f / z1;
        const float pxf1 = fminf(fmaxf((rx*dv1 + tx)*rz1, -8.f), 168.f);
        const float pyf1 = fminf(fmaxf((ry*dv1 + ty)*rz1, -8.f), 136.f);
        const float wx1b = pxf1 - fx, wy1b = pyf1 - fy;
        pwbxO = pkh2((1.f - wx1b)*mxl, wx1b*mxh);
        pwbyO = pkh2((1.f - wy1b)*myl, wy1b*myh);
        if (!pokI) { pwaxO = 0u; pwayO = 0u; pwbxO = 0u; pwbyO = 0u; }
    };

    // prologue: pass-0 geometry + ref-feature + projection
    bool pok; int rp, lx, ly;
    mk(wv, pok, rp, lx, ly);
    h8 fr = F[(size_t)rp*4 + grp];
    unsigned pidx, pwax, pway, pwbx, pwby;
    PROJ(pok, lx, ly, pidx, pwax, pway, pwbx, pwby);

    #pragma unroll 1
    for (int pass = 0; pass < 6; ++pass) {
        const int tile = pass*4 + wv;          // wave-uniform

        // ---- next pass: geometry, fr load (in flight), projection (VALU
        //      fills this pass's gather stalls) ----
        bool pokN = false; int rpN = 0, lxN = 0, lyN = 0;
        h8 frN = hz;
        unsigned pidxN = 0u, pwaxN = 0u, pwayN = 0u, pwbxN = 0u, pwbyN = 0u;
        if (pass < 5) {
            mk(tile + 4, pokN, rpN, lxN, lyN);
            frN = F[(size_t)rpN*4 + grp];
            PROJ(pokN, lxN, lyN, pidxN, pwaxN, pwayN, pwbxN, pwbyN);
        }

        if (tile < NT) {
            // ---- batched shuffles: all 4 views' params up front ----
            unsigned iv[4], axv[4], ayv[4], bxv[4], byv[4];
            #pragma unroll
            for (int v = 0; v < 4; ++v) {
                const int src = v*16 + n;
                iv[v]  = (unsigned)__shfl((int)pidx, src, 64);
                axv[v] = (unsigned)__shfl((int)pwax, src, 64);
                ayv[v] = (unsigned)__shfl((int)pway, src, 64);
                bxv[v] = (unsigned)__shfl((int)pwbx, src, 64);
                byv[v] = (unsigned)__shfl((int)pwby, src, 64);
            }

            // ---- gather: 1-deep corner-load rotation, FMA order v0..v3 ----
            h8 var0 = hz, var1 = hz;
            h8 s0 = hz, q0 = hz, s1 = hz, q1 = hz;
            if (pok) {
                s0 = fr; q0 = fr*fr; s1 = fr; q1 = q0;
            }

            h8 f00 = hz, f10 = hz, f01 = hz, f11 = hz;
            if (pok) {
                const unsigned i0 = iv[0];
                const int x0 = i0 & 0xff, x1 = (i0 >> 8) & 0xff;
                const int y0W = ((i0 >> 16) & 0xff) * W_;
                const int y1W = (i0 >> 24) * W_;
                const h8* Fv = F + (size_t)1*HW_*4;
                f00 = Fv[(size_t)(y0W+x0)*4 + grp];
                f10 = Fv[(size_t)(y0W+x1)*4 + grp];
                f01 = Fv[(size_t)(y1W+x0)*4 + grp];
                f11 = Fv[(size_t)(y1W+x1)*4 + grp];
            }

            #pragma unroll
            for (int v = 0; v < 4; ++v) {
                // issue view v+1's corner loads (params already shuffled)
                h8 n00 = hz, n10 = hz, n01 = hz, n11 = hz;
                if (v < 3) {
                    if (pok) {
                        const unsigned ii = iv[v+1];
                        const int x0 = ii & 0xff, x1 = (ii >> 8) & 0xff;
                        const int y0W = ((ii >> 16) & 0xff) * W_;
                        const int y1W = (ii >> 24) * W_;
                        const h8* Fv = F + (size_t)(v+2)*HW_*4;
                        n00 = Fv[(size_t)(y0W+x0)*4 + grp];
                        n10 = Fv[(size_t)(y0W+x1)*4 + grp];
                        n01 = Fv[(size_t)(y1W+x0)*4 + grp];
                        n11 = Fv[(size_t)(y1W+x1)*4 + grp];
                    }
                }
                if (pok) {
                    const _Float16 wx0a = u2h(axv[v]), wx1a = u2h(axv[v] >> 16);
                    const _Float16 wy0a = u2h(ayv[v]), wy1a = u2h(ayv[v] >> 16);
                    const h8 t0a = f00*wx0a + f10*wx1a;
                    const h8 t1a = f01*wx0a + f11*wx1a;
                    const h8 g0 = t0a*wy0a + t1a*wy1a;
                    s0 += g0; q0 += g0*g0;
                    const _Float16 wx0b = u2h(bxv[v]), wx1b = u2h(bxv[v] >> 16);
                    const _Float16 wy0b = u2h(byv[v]), wy1b = u2h(byv[v] >> 16);
                    const h8 t0b = f00*wx0b + f10*wx1b;
                    const h8 t1b = f01*wx0b + f11*wx1b;
                    const h8 g1 = t0b*wy0b + t1b*wy1b;
                    s1 += g1; q1 += g1*g1;
                }
                // rotate (renamed by full unroll, no movs)
                f00 = n00; f10 = n10; f01 = n01; f11 = n11;
            }

            if (pok) {
                const _Float16 c5 = (_Float16)0.2f;
                const h8 sa = s0 * c5, sb = s1 * c5;
                var0 = q0*c5 - sa*sa;
                var1 = q1*c5 - sb*sb;
            }
            // variance already in MFMA A-layout: lane holds A[px=n][k=grp*8..+8]
            const f4 a0 = __builtin_amdgcn_mfma_f32_16x16x32_f16(var0, bf0, fz, 0, 0, 0);
            const f4 b0 = __builtin_amdgcn_mfma_f32_16x16x32_f16(var0, bf1, fz, 0, 0, 0);
            const f4 a1 = __builtin_amdgcn_mfma_f32_16x16x32_f16(var1, bf0, fz, 0, 0, 0);
            const f4 b1 = __builtin_amdgcn_mfma_f32_16x16x32_f16(var1, bf1, fz, 0, 0, 0);
            const int rbase = tile*16 + grp*4;
            #pragma unroll
            for (int r = 0; r < 4; ++r) {
                unsigned* dr = &DLP[(rbase + r)*DSTW];
                dr[n] = pkh2(a0[r], a1[r]);
                if (n < 11) dr[16 + n] = pkh2(b0[r], b1[r]);
            }
        }

        // rotate pass state
        pok = pokN; rp = rpN; lx = lxN; ly = lyN; fr = frN;
        pidx = pidxN; pwax = pwaxN; pway = pwayN; pwbx = pwbxN; pwby = pwbyN;
    }
    __syncthreads();

    // ---- 27-term spatial shifted sum -> Q[kd][d][p], both depths ----
    {
        const int x = tid & 15;
        const int y = tid >> 4;
        float c00 = 0.f, c01 = 0.f, c02 = 0.f;
        float c10 = 0.f, c11 = 0.f, c12 = 0.f;
        #pragma unroll
        for (int jy = 0; jy < 3; ++jy) {
            #pragma unroll
            for (int jx = 0; jx < 3; ++jx) {
                const int sp = jy*3 + jx;
                const unsigned* dr = &DLP[((y + jy)*HPX + (x + jx))*DSTW];
                const unsigned u0 = dr[sp];
                const unsigned u1 = dr[9 + sp];
                const unsigned u2 = dr[18 + sp];
                c00 += (float)u2h(u0);  c10 += (float)u2h(u0 >> 16);
                c01 += (float)u2h(u1);  c11 += (float)u2h(u1 >> 16);
                c02 += (float)u2h(u2);  c12 += (float)u2h(u2 >> 16);
            }
        }
        const int p = (by*TY + y)*W_ + bx*TX + x;
        Q[(size_t)(0*D_ + d0)*HW_ + p] = c00;
        Q[(size_t)(1*D_ + d0)*HW_ + p] = c01;
        Q[(size_t)(2*D_ + d0)*HW_ + p] = c02;
        Q[(size_t)(0*D_ + d1)*HW_ + p] = c10;
        Q[(size_t)(1*D_ + d1)*HW_ + p] = c11;
        Q[(size_t)(2*D_ + d1)*HW_ + p] = c12;
    }
}

// Finalize: combine depth taps, softmax over D, depth + confidence.
// Repartitioned for latency hiding: 128-thread blocks (4 depth-groups x
// 32 px), grid 640 (2.5 blocks/CU vs old 1.25). Same 4-way depth-group
// combine tree and FP order per pixel — pure repartition. kB was the ~22us
// win in r6 via the same lever (more waves); this doubles block-level
// parallelism for its 36 scattered loads/thread.
__global__ __launch_bounds__(128) void kB(const float* __restrict__ Q,
                                          const float* __restrict__ dvals,
                                          float* __restrict__ out) {
    __shared__ float Rm[4][32], Sm[4][32], Sd[4][32], Si[4][32], Cf[4][32];
    const int tid = threadIdx.x;
    const int l = tid & 31;        // px-in-block
    const int w = tid >> 5;        // depth-group 0..3
    const int p = blockIdx.x*32 + l;
    const int db = w*12;
    const float* Q0 = Q;
    const float* Q1 = Q + (size_t)D_*HW_;
    const float* Q2 = Q + (size_t)2*D_*HW_;

    float c[12];
    #pragma unroll
    for (int j = 0; j < 12; ++j) {
        const int dd = db + j;
        float v = Q1[dd*HW_ + p];
        if (dd > 0)     v += Q0[(dd-1)*HW_ + p];
        if (dd < D_-1)  v += Q2[(dd+1)*HW_ + p];
        c[j] = v;
    }
    float lm = c[0];
    #pragma unroll
    for (int j = 1; j < 12; ++j) lm = fmaxf(lm, c[j]);
    Rm[w][l] = lm;
    __syncthreads();
    const float gm = fmaxf(fmaxf(Rm[0][l], Rm[1][l]), fmaxf(Rm[2][l], Rm[3][l]));

    float e[12];
    float ls = 0.f, lsd = 0.f, lsi = 0.f;
    #pragma unroll
    for (int j = 0; j < 12; ++j) {
        const int dd = db + j;
        const float ev = __expf(c[j] - gm);
        e[j] = ev;
        ls  += ev;
        lsd += ev * dvals[dd];
        lsi += ev * (float)dd;
    }
    Sm[w][l] = ls; Sd[w][l] = lsd; Si[w][l] = lsi;
    __syncthreads();
    const float ts  = Sm[0][l] + Sm[1][l] + Sm[2][l] + Sm[3][l];
    const float tsd = Sd[0][l] + Sd[1][l] + Sd[2][l] + Sd[3][l];
    const float tsi = Si[0][l] + Si[1][l] + Si[2][l] + Si[3][l];
    const float is = 1.f / ts;
    int di = (int)(tsi * is);
    di = di < 0 ? 0 : (di > D_-1 ? D_-1 : di);

    float lc = 0.f;
    #pragma unroll
    for (int j = 0; j < 12; ++j) {
        const int dd = db + j;
        lc += ((dd >= di-1) && (dd <= di+2)) ? e[j] : 0.f;
    }
    Cf[w][l] = lc;
    __syncthreads();
    if (w == 0) {
        out[p] = tsd * is;
        out[HW_ + p] = (Cf[0][l] + Cf[1][l] + Cf[2][l] + Cf[3][l]) * is;
    }
}

extern "C" void kernel_launch(void* const* d_in, const int* in_sizes, int n_in,
                              void* d_out, int out_size, void* d_ws, size_t ws_size,
                              hipStream_t stream) {
    const float* features = (const float*)d_in[0];
    const float* proj     = (const float*)d_in[1];
    const float* dvals    = (const float*)d_in[2];
    const float* regw     = (const float*)d_in[3];
    float* out = (float*)d_out;

    _Float16* featH = (_Float16*)d_ws;                       // 5*HW*32 f16 = 6.55 MB
    float* M  = (float*)(featH + (size_t)5*HW_*C_);          // 48 floats (+pad)
    float* Q  = M + 64;                                      // 3*48*HW f32 = 11.8 MB

    kS<<<dim3(321, 5), 256, 0, stream>>>(features, proj, featH, M);
    kA<<<dim3(W_/TX, H_/TY, D_/2), 256, 0, stream>>>(featH, M, dvals, regw, Q);
    kB<<<HW_/32, 128, 0, stream>>>(Q, dvals, out);
}